// Round 1
// baseline (401.643 us; speedup 1.0000x reference)
//
#include <hip/hip_runtime.h>
#include <math.h>

#define B_ 8
#define C_ 64
#define H_ 128
#define W_ 128
#define O_ 64
#define HW (H_*W_)
#define KK 9

// ws layout (in floats)
#define OFF_BUF  0
#define MASK_BUF (B_*18*HW)            // 2359296
#define WA_BUF   (MASK_BUF + B_*9*HW)  // 3538944
#define WB_BUF   (WA_BUF + C_*KK*32)   // 3557376
// total floats: 3594240  (~13.7 MiB)

// Pre-transpose weights:
//  wA[c][k][32]: oc 0..17 = offset_w[oc][c][k], oc 18..26 = mod_w[oc-18][c][k], pad 0
//  wB[c][k][64]: weight[oc][c][k]
__global__ void prep_weights(const float* __restrict__ offw,
                             const float* __restrict__ modw,
                             const float* __restrict__ w,
                             float* __restrict__ ws) {
    int t = blockIdx.x * 256 + threadIdx.x;
    const int nA = C_ * KK * 32;
    if (t < nA) {
        int oc = t & 31;
        int ck = t >> 5;
        int c = ck / KK, k = ck % KK;
        float v = 0.f;
        if (oc < 18)      v = offw[oc * (C_ * KK) + c * KK + k];
        else if (oc < 27) v = modw[(oc - 18) * (C_ * KK) + c * KK + k];
        ws[WA_BUF + t] = v;
    } else {
        int t2 = t - nA;
        if (t2 < C_ * KK * O_) {
            int oc = t2 & 63;
            int ck = t2 >> 6;
            int c = ck / KK, k = ck % KK;
            ws[WB_BUF + t2] = w[oc * (C_ * KK) + c * KK + k];
        }
    }
}

// 3x3 conv, 27 output channels (18 offset clipped +-32, 9 modulator 2*sigmoid)
__global__ __launch_bounds__(256) void conv_a(const float* __restrict__ x,
                                              const float* __restrict__ offb,
                                              const float* __restrict__ modb,
                                              float* __restrict__ ws) {
    int tx = threadIdx.x & 15, ty = threadIdx.x >> 4;
    int b = blockIdx.z;
    int xx = blockIdx.x * 16 + tx;
    int yy = blockIdx.y * 16 + ty;

    float acc[27];
#pragma unroll
    for (int oc = 0; oc < 18; oc++) acc[oc] = offb[oc];
#pragma unroll
    for (int oc = 0; oc < 9; oc++)  acc[18 + oc] = modb[oc];

    // 9 taps: clamped index + validity flag (zero-pad conv)
    int idx[9];
    float fl[9];
#pragma unroll
    for (int ky = 0; ky < 3; ky++)
#pragma unroll
        for (int kx = 0; kx < 3; kx++) {
            int yo = yy + ky - 1, xo = xx + kx - 1;
            bool v = (yo >= 0) && (yo < H_) && (xo >= 0) && (xo < W_);
            int yc = min(max(yo, 0), H_ - 1);
            int xc = min(max(xo, 0), W_ - 1);
            idx[ky * 3 + kx] = yc * W_ + xc;
            fl[ky * 3 + kx] = v ? 1.f : 0.f;
        }

    const float* xb = x + (size_t)b * C_ * HW;
    const float* wA = ws + WA_BUF;

    for (int c = 0; c < C_; c++) {
        float xv[9];
#pragma unroll
        for (int k = 0; k < 9; k++) xv[k] = xb[c * HW + idx[k]] * fl[k];
#pragma unroll
        for (int k = 0; k < 9; k++) {
            const float* wr = wA + (c * 9 + k) * 32;   // uniform -> s_load
#pragma unroll
            for (int oc = 0; oc < 27; oc++)
                acc[oc] = fmaf(xv[k], wr[oc], acc[oc]);
        }
    }

    int pix = yy * W_ + xx;
    float* offo = ws + OFF_BUF + (size_t)b * 18 * HW;
#pragma unroll
    for (int oc = 0; oc < 18; oc++) {
        float v = fminf(fmaxf(acc[oc], -32.f), 32.f);   // max_offset = 128/4
        offo[oc * HW + pix] = v;
    }
    float* msko = ws + MASK_BUF + (size_t)b * 9 * HW;
#pragma unroll
    for (int oc = 0; oc < 9; oc++) {
        float s = 2.f / (1.f + __expf(-acc[18 + oc]));
        msko[oc * HW + pix] = s;
    }
}

// deformable conv: bilinear gather + einsum('bckhw,ock->bohw')
__global__ __launch_bounds__(256) void deform(const float* __restrict__ x,
                                              const float* __restrict__ ws,
                                              float* __restrict__ out) {
    int tx = threadIdx.x & 15, ty = threadIdx.x >> 4;
    int b = blockIdx.z;
    int xx = blockIdx.x * 16 + tx;
    int yy = blockIdx.y * 16 + ty;
    int pix = yy * W_ + xx;

    const float* offp = ws + OFF_BUF + (size_t)b * 18 * HW + pix;
    const float* mskp = ws + MASK_BUF + (size_t)b * 9 * HW + pix;
    const float* xb = x + (size_t)b * C_ * HW;
    const float* wB = ws + WB_BUF;

    float acc[64];
#pragma unroll
    for (int o = 0; o < 64; o++) acc[o] = 0.f;

    for (int ky = 0; ky < 3; ky++) {
        for (int kx = 0; kx < 3; kx++) {
            int k = ky * 3 + kx;
            float dy = offp[(2 * k) * HW];
            float dx = offp[(2 * k + 1) * HW];
            float m  = mskp[k * HW];

            float py = (float)(yy + ky - 1) + dy;
            float px = (float)(xx + kx - 1) + dx;
            float fy = floorf(py), fx = floorf(px);
            int y0 = (int)fy, x0 = (int)fx;
            float wy = py - fy, wx = px - fx;

            bool vy0 = (y0 >= 0) && (y0 < H_);
            bool vy1 = (y0 + 1 >= 0) && (y0 + 1 < H_);
            bool vx0 = (x0 >= 0) && (x0 < W_);
            bool vx1 = (x0 + 1 >= 0) && (x0 + 1 < W_);
            int yc0 = min(max(y0, 0), H_ - 1);
            int yc1 = min(max(y0 + 1, 0), H_ - 1);
            int xc0 = min(max(x0, 0), W_ - 1);
            int xc1 = min(max(x0 + 1, 0), W_ - 1);

            float e00 = (1.f - wy) * (1.f - wx) * m * ((vy0 && vx0) ? 1.f : 0.f);
            float e01 = (1.f - wy) * wx         * m * ((vy0 && vx1) ? 1.f : 0.f);
            float e10 = wy * (1.f - wx)         * m * ((vy1 && vx0) ? 1.f : 0.f);
            float e11 = wy * wx                 * m * ((vy1 && vx1) ? 1.f : 0.f);

            int i00 = yc0 * W_ + xc0;
            int i01 = yc0 * W_ + xc1;
            int i10 = yc1 * W_ + xc0;
            int i11 = yc1 * W_ + xc1;

            for (int c = 0; c < C_; c++) {
                const float* xc = xb + c * HW;
                float v = e00 * xc[i00] + e01 * xc[i01]
                        + e10 * xc[i10] + e11 * xc[i11];
                const float* wr = wB + (c * 9 + k) * 64;   // uniform -> s_load
#pragma unroll
                for (int o = 0; o < 64; o++)
                    acc[o] = fmaf(v, wr[o], acc[o]);
            }
        }
    }

    float* op = out + (size_t)b * O_ * HW + pix;
#pragma unroll
    for (int o = 0; o < 64; o++) op[o * HW] = acc[o];
}

extern "C" void kernel_launch(void* const* d_in, const int* in_sizes, int n_in,
                              void* d_out, int out_size, void* d_ws, size_t ws_size,
                              hipStream_t stream) {
    const float* x    = (const float*)d_in[0];
    const float* offw = (const float*)d_in[1];
    const float* offb = (const float*)d_in[2];
    const float* modw = (const float*)d_in[3];
    const float* modb = (const float*)d_in[4];
    const float* w    = (const float*)d_in[5];
    float* out = (float*)d_out;
    float* ws  = (float*)d_ws;

    int nprep = C_ * KK * 32 + C_ * KK * 64;   // 55296
    prep_weights<<<dim3((nprep + 255) / 256), dim3(256), 0, stream>>>(offw, modw, w, ws);

    dim3 grid(W_ / 16, H_ / 16, B_);
    dim3 blk(256);
    conv_a<<<grid, blk, 0, stream>>>(x, offb, modb, ws);
    deform<<<grid, blk, 0, stream>>>(x, ws, out);
}